// Round 16
// baseline (50.088 us; speedup 1.0000x reference)
//
#include <hip/hip_runtime.h>

namespace {

typedef float f2 __attribute__((ext_vector_type(2)));

constexpr int FR = 64;    // frames per block

constexpr float F_F  = 512.0f;
constexpr float PX_F = 512.0f;
constexpr float PY_F = 288.0f;
constexpr float EPS_F = 1e-8f;

// weights folded with per-loss divisors
constexpr float WPROJ   = 0.25f / (2.0f * 21.0f);
constexpr float WLIFT   = 0.25f / (3.0f * 21.0f);
constexpr float WBONE   = 0.25f / 20.0f;
constexpr float WSMOOTH = 0.25f / (3.0f * 21.0f);

__device__ __forceinline__ double block_reduce(double val) {
    __shared__ double smem[16];
    const int lane = threadIdx.x & 63;
    const int wid  = threadIdx.x >> 6;
    #pragma unroll
    for (int off = 32; off > 0; off >>= 1)
        val += __shfl_down(val, off, 64);
    if (lane == 0) smem[wid] = val;
    __syncthreads();
    if (wid == 0) {
        const int nw = blockDim.x >> 6;
        val = (lane < nw) ? smem[lane] : 0.0;
        #pragma unroll
        for (int off = 32; off > 0; off >>= 1)
            val += __shfl_down(val, off, 64);
    }
    return val;
}

__global__ __launch_bounds__(256) void pose_loss_kernel(
    const float* __restrict__ pose3d,      // (W+1, 3, 21)
    const float* __restrict__ bone_2d,     // (W, 2, 21)
    const float* __restrict__ lift_dirs,   // (W, 3, 20)
    const float* __restrict__ R_drone,     // (W, 3, 3)
    const float* __restrict__ C_drone,     // (W, 3, 1)
    const float* __restrict__ bone_len,    // (20,)
    const float* __restrict__ R_cam,       // (3,3)
    float* __restrict__ out,               // single float, zeroed before launch
    int W)
{
    // pose 16.6 KB + M 3 KB -> ~19.7 KB -> 8 blocks/CU by LDS
    __shared__ alignas(16) float s_pose[(FR + 2) * 63 + 2];
    // permuted per-frame M row (stride 12):
    // [0..1]={M0,M3} [2..3]={M1,M4} [4..5]={M2,M5} [6..7]={MC0,MC1}
    // [8..11]={M6,M7,M8,MC2}
    __shared__ alignas(16) float s_M[FR * 12];

    const int tid = threadIdx.x;
    const int w0  = blockIdx.x * FR;
    const int nF  = min(FR, W - w0);
    const int nPoseF = min(FR + 2, W + 1 - w0);

    // ---------- stage pose (coalesced float4; base w0*63 is 16B-aligned) ----------
    {
        const float* src = pose3d + (size_t)w0 * 63;
        const int nfl = nPoseF * 63;
        const int n4 = nfl >> 2;
        const float4* s4 = (const float4*)src;
        float4* d4 = (float4*)s_pose;
        for (int i = tid; i < n4; i += 256) d4[i] = s4[i];
        for (int i = (n4 << 2) + tid; i < nfl; i += 256) s_pose[i] = src[i];
    }

    // ---------- per-frame M = R_cam @ Rd^T, MC = M @ C (threads 0..nF-1) ----------
    if (tid < nF) {
        const float* Rd = R_drone + (size_t)(w0 + tid) * 9;
        float rd[9];
        #pragma unroll
        for (int k = 0; k < 9; ++k) rd[k] = Rd[k];
        float rc[9];
        #pragma unroll
        for (int k = 0; k < 9; ++k) rc[k] = R_cam[k];   // uniform -> s_load
        float M[9];
        #pragma unroll
        for (int i = 0; i < 3; ++i)
            #pragma unroll
            for (int k = 0; k < 3; ++k)
                M[i * 3 + k] = rc[i * 3 + 0] * rd[k * 3 + 0]
                             + rc[i * 3 + 1] * rd[k * 3 + 1]
                             + rc[i * 3 + 2] * rd[k * 3 + 2];
        const float* Cp = C_drone + (size_t)(w0 + tid) * 3;
        const float C0 = Cp[0], C1 = Cp[1], C2 = Cp[2];
        float MC[3];
        #pragma unroll
        for (int i = 0; i < 3; ++i)
            MC[i] = M[i * 3 + 0] * C0 + M[i * 3 + 1] * C1 + M[i * 3 + 2] * C2;
        float* mb = s_M + tid * 12;
        mb[0] = M[0]; mb[1] = M[3]; mb[2]  = M[1]; mb[3]  = M[4];
        mb[4] = M[2]; mb[5] = M[5]; mb[6]  = MC[0]; mb[7] = MC[1];
        mb[8] = M[6]; mb[9] = M[7]; mb[10] = M[8]; mb[11] = MC[2];
    }
    __syncthreads();

    float partial = 0.0f;

    // fixed-j mapping: 252 active threads = 12 frame-groups x 21 joints
    if (tid < 252) {
        const int j = tid % 21;
        const int g = tid / 21;
        const bool hasBone = (j < 20);
        const float blj = hasBone ? bone_len[j] : 0.0f;

        for (int wl = g; wl < nF; wl += 12) {
            const int w = w0 + wl;
            const float* P0 = s_pose + wl * 63;
            const float* P1 = P0 + 63;
            const float* mb = s_M + wl * 12;

            const float x0 = P1[j], y0 = P1[21 + j], z0 = P1[42 + j];

            // ---- projection (pk math; fast rcp) ----
            {
                const f2 A = *(const f2*)(mb + 0);
                const f2 B = *(const f2*)(mb + 2);
                const f2 C = *(const f2*)(mb + 4);
                const f2 D = *(const f2*)(mb + 6);
                const float4 E = *(const float4*)(mb + 8);   // M6,M7,M8,MC2
                f2 c01 = A * x0 + B * y0 + C * z0 - D;
                const float c2 = E.x * x0 + E.y * y0 + E.z * z0 - E.w;
                const float invz = __builtin_amdgcn_rcpf(c2);
                f2 uv = c01 * (F_F * invz) + (f2){PX_F, PY_F};
                const f2 b2 = { bone_2d[(size_t)w * 42 + j],
                                bone_2d[(size_t)w * 42 + 21 + j] };
                const f2 duv = uv - b2;
                partial += WPROJ * (duv.x * duv.x + duv.y * duv.y);
            }

            if (hasBone) {
                // ---- lift (frame w+1 bone direction) ----
                const float ax = P1[j + 1]      - x0;
                const float ay = P1[21 + j + 1] - y0;
                const float az = P1[42 + j + 1] - z0;
                const float q  = ax * ax + ay * ay + az * az;
                const float inv = __builtin_amdgcn_rcpf(
                                      __builtin_amdgcn_sqrtf(q) + EPS_F);
                const float lx = lift_dirs[(size_t)w * 60 + j]      - ax * inv;
                const float ly = lift_dirs[(size_t)w * 60 + 20 + j] - ay * inv;
                const float lz = lift_dirs[(size_t)w * 60 + 40 + j] - az * inv;
                partial += WLIFT * (lx * lx + ly * ly + lz * lz);

                // ---- bone (frame w) ----
                const float bx = P0[j + 1]      - P0[j];
                const float by = P0[21 + j + 1] - P0[21 + j];
                const float bz = P0[42 + j + 1] - P0[42 + j];
                const float e = blj - (bx * bx + by * by + bz * bz);
                partial += WBONE * (e * e);
                if (w == W - 1) {              // frame W == P1 here; |bone|^2 == q
                    const float e2 = blj - q;
                    partial += WBONE * (e2 * e2);
                }
            }

            // ---- smoothness (t = w) ----
            if (w < W - 1) {
                const float* P2 = P0 + 126;
                const float sx = P2[j]      - 2.0f * x0 + P0[j];
                const float sy = P2[21 + j] - 2.0f * y0 + P0[21 + j];
                const float sz = P2[42 + j] - 2.0f * z0 + P0[42 + j];
                partial += WSMOOTH * (sx * sx + sy * sy + sz * sz);
            }
        }
    }

    const double bsum = block_reduce((double)partial);
    // fused tail: ONE relaxed device-scope atomicAdd per block (no ordered
    // atomics / no polling -- that was the R6/R8 100-us poison).
    if (tid == 0) atomicAdd(out, (float)bsum);
}

}  // namespace

extern "C" void kernel_launch(void* const* d_in, const int* in_sizes, int n_in,
                              void* d_out, int out_size, void* d_ws, size_t ws_size,
                              hipStream_t stream) {
    const float* pose3d    = (const float*)d_in[0];
    const float* bone_2d   = (const float*)d_in[1];
    const float* lift_dirs = (const float*)d_in[2];
    const float* R_drone   = (const float*)d_in[3];
    const float* C_drone   = (const float*)d_in[4];
    const float* bone_len  = (const float*)d_in[5];
    const float* R_cam     = (const float*)d_in[6];
    float* out = (float*)d_out;

    const int W = in_sizes[3] / 9;       // R_drone is (W,3,3)
    const int grid = (W + FR - 1) / FR;  // 2048 for W=131072

    hipMemsetAsync(out, 0, sizeof(float), stream);

    pose_loss_kernel<<<grid, 256, 0, stream>>>(
        pose3d, bone_2d, lift_dirs, R_drone, C_drone, bone_len, R_cam, out, W);
}

// Round 17
// 27.264 us; speedup vs baseline: 1.8372x; 1.8372x over previous
//
#include <hip/hip_runtime.h>

namespace {

typedef float f2 __attribute__((ext_vector_type(2)));

constexpr int FR = 60;    // frames per block: 12 groups x 5 frames, exactly balanced

constexpr float F_F  = 512.0f;
constexpr float PX_F = 512.0f;
constexpr float PY_F = 288.0f;
constexpr float EPS_F = 1e-8f;

// weights folded with per-loss divisors
constexpr float WPROJ   = 0.25f / (2.0f * 21.0f);
constexpr float WLIFT   = 0.25f / (3.0f * 21.0f);
constexpr float WBONE   = 0.25f / 20.0f;
constexpr float WSMOOTH = 0.25f / (3.0f * 21.0f);

__device__ __forceinline__ double block_reduce(double val) {
    __shared__ double smem[16];
    const int lane = threadIdx.x & 63;
    const int wid  = threadIdx.x >> 6;
    #pragma unroll
    for (int off = 32; off > 0; off >>= 1)
        val += __shfl_down(val, off, 64);
    if (lane == 0) smem[wid] = val;
    __syncthreads();
    if (wid == 0) {
        const int nw = blockDim.x >> 6;
        val = (lane < nw) ? smem[lane] : 0.0;
        #pragma unroll
        for (int off = 32; off > 0; off >>= 1)
            val += __shfl_down(val, off, 64);
    }
    return val;
}

__global__ __launch_bounds__(256) void pose_loss_kernel(
    const float* __restrict__ pose3d,      // (W+1, 3, 21)
    const float* __restrict__ bone_2d,     // (W, 2, 21)
    const float* __restrict__ lift_dirs,   // (W, 3, 20)
    const float* __restrict__ R_drone,     // (W, 3, 3)
    const float* __restrict__ C_drone,     // (W, 3, 1)
    const float* __restrict__ bone_len,    // (20,)
    const float* __restrict__ R_cam,       // (3,3)
    float* __restrict__ partials,          // (gridDim.x,)
    int W)
{
    // pose (60+2)*63 = 3906 floats + M 60*12 = 720 floats -> ~18.5 KB -> 8 blocks/CU
    __shared__ alignas(16) float s_pose[(FR + 2) * 63 + 2];
    // permuted per-frame M row (stride 12):
    // [0..1]={M0,M3} [2..3]={M1,M4} [4..5]={M2,M5} [6..7]={MC0,MC1}
    // [8..11]={M6,M7,M8,MC2}
    __shared__ alignas(16) float s_M[FR * 12];

    const int tid = threadIdx.x;
    const int w0  = blockIdx.x * FR;
    const int nF  = min(FR, W - w0);
    const int nPoseF = min(FR + 2, W + 1 - w0);

    // ---------- stage pose (coalesced float4; base w0*63 = blk*3780, 16B-aligned) ----------
    {
        const float* src = pose3d + (size_t)w0 * 63;
        const int nfl = nPoseF * 63;
        const int n4 = nfl >> 2;
        const float4* s4 = (const float4*)src;
        float4* d4 = (float4*)s_pose;
        for (int i = tid; i < n4; i += 256) d4[i] = s4[i];
        for (int i = (n4 << 2) + tid; i < nfl; i += 256) s_pose[i] = src[i];
    }

    // ---------- per-frame M = R_cam @ Rd^T, MC = M @ C (threads 0..nF-1) ----------
    if (tid < nF) {
        const float* Rd = R_drone + (size_t)(w0 + tid) * 9;
        float rd[9];
        #pragma unroll
        for (int k = 0; k < 9; ++k) rd[k] = Rd[k];
        float rc[9];
        #pragma unroll
        for (int k = 0; k < 9; ++k) rc[k] = R_cam[k];   // uniform -> s_load
        float M[9];
        #pragma unroll
        for (int i = 0; i < 3; ++i)
            #pragma unroll
            for (int k = 0; k < 3; ++k)
                M[i * 3 + k] = rc[i * 3 + 0] * rd[k * 3 + 0]
                             + rc[i * 3 + 1] * rd[k * 3 + 1]
                             + rc[i * 3 + 2] * rd[k * 3 + 2];
        const float* Cp = C_drone + (size_t)(w0 + tid) * 3;
        const float C0 = Cp[0], C1 = Cp[1], C2 = Cp[2];
        float MC[3];
        #pragma unroll
        for (int i = 0; i < 3; ++i)
            MC[i] = M[i * 3 + 0] * C0 + M[i * 3 + 1] * C1 + M[i * 3 + 2] * C2;
        float* mb = s_M + tid * 12;
        mb[0] = M[0]; mb[1] = M[3]; mb[2]  = M[1]; mb[3]  = M[4];
        mb[4] = M[2]; mb[5] = M[5]; mb[6]  = MC[0]; mb[7] = MC[1];
        mb[8] = M[6]; mb[9] = M[7]; mb[10] = M[8]; mb[11] = MC[2];
    }
    __syncthreads();

    float partial = 0.0f;

    // fixed-j mapping: 252 active threads = 12 frame-groups x 21 joints;
    // thread handles frames wl = g + 12k. For full blocks (nF==60) this is
    // EXACTLY 5 iterations for every thread -> static unroll, no guards,
    // letting the compiler software-pipeline the stream loads itself.
    if (tid < 252) {
        const int j = tid % 21;
        const int g = tid / 21;
        const bool hasBone = (j < 20);
        const float blj = hasBone ? bone_len[j] : 0.0f;

        auto body = [&](int wl) {
            const int w = w0 + wl;
            const float* P0 = s_pose + wl * 63;
            const float* P1 = P0 + 63;
            const float* mb = s_M + wl * 12;

            const float x0 = P1[j], y0 = P1[21 + j], z0 = P1[42 + j];

            // ---- projection (pk math; fast rcp) ----
            {
                const f2 A = *(const f2*)(mb + 0);
                const f2 B = *(const f2*)(mb + 2);
                const f2 C = *(const f2*)(mb + 4);
                const f2 D = *(const f2*)(mb + 6);
                const float4 E = *(const float4*)(mb + 8);   // M6,M7,M8,MC2
                f2 c01 = A * x0 + B * y0 + C * z0 - D;
                const float c2 = E.x * x0 + E.y * y0 + E.z * z0 - E.w;
                const float invz = __builtin_amdgcn_rcpf(c2);
                f2 uv = c01 * (F_F * invz) + (f2){PX_F, PY_F};
                const f2 b2 = { bone_2d[(size_t)w * 42 + j],
                                bone_2d[(size_t)w * 42 + 21 + j] };
                const f2 duv = uv - b2;
                partial += WPROJ * (duv.x * duv.x + duv.y * duv.y);
            }

            if (hasBone) {
                // ---- lift (frame w+1 bone direction) ----
                const float ax = P1[j + 1]      - x0;
                const float ay = P1[21 + j + 1] - y0;
                const float az = P1[42 + j + 1] - z0;
                const float q  = ax * ax + ay * ay + az * az;
                const float inv = __builtin_amdgcn_rcpf(
                                      __builtin_amdgcn_sqrtf(q) + EPS_F);
                const float lx = lift_dirs[(size_t)w * 60 + j]      - ax * inv;
                const float ly = lift_dirs[(size_t)w * 60 + 20 + j] - ay * inv;
                const float lz = lift_dirs[(size_t)w * 60 + 40 + j] - az * inv;
                partial += WLIFT * (lx * lx + ly * ly + lz * lz);

                // ---- bone (frame w) ----
                const float bx = P0[j + 1]      - P0[j];
                const float by = P0[21 + j + 1] - P0[21 + j];
                const float bz = P0[42 + j + 1] - P0[42 + j];
                const float e = blj - (bx * bx + by * by + bz * bz);
                partial += WBONE * (e * e);
                if (w == W - 1) {              // frame W == P1 here; |bone|^2 == q
                    const float e2 = blj - q;
                    partial += WBONE * (e2 * e2);
                }
            }

            // ---- smoothness (t = w) ----
            if (w < W - 1) {
                const float* P2 = P0 + 126;
                const float sx = P2[j]      - 2.0f * x0 + P0[j];
                const float sy = P2[21 + j] - 2.0f * y0 + P0[21 + j];
                const float sz = P2[42 + j] - 2.0f * z0 + P0[42 + j];
                partial += WSMOOTH * (sx * sx + sy * sy + sz * sz);
            }
        };

        if (nF == FR) {
            #pragma unroll
            for (int k = 0; k < 5; ++k) body(g + 12 * k);
        } else {
            for (int wl = g; wl < nF; wl += 12) body(wl);
        }
    }

    const double bsum = block_reduce((double)partial);
    if (tid == 0) partials[blockIdx.x] = (float)bsum;
}

__global__ __launch_bounds__(256) void final_reduce_kernel(
    const float* __restrict__ partials, float* __restrict__ out, int n)
{
    double v = 0.0;
    const int n4 = n >> 2;
    const float4* p4 = (const float4*)partials;
    for (int i = threadIdx.x; i < n4; i += blockDim.x) {
        const float4 x = p4[i];
        v += (double)x.x + (double)x.y + (double)x.z + (double)x.w;
    }
    for (int i = (n4 << 2) + threadIdx.x; i < n; i += blockDim.x)
        v += (double)partials[i];
    v = block_reduce(v);
    if (threadIdx.x == 0) out[0] = (float)v;
}

}  // namespace

extern "C" void kernel_launch(void* const* d_in, const int* in_sizes, int n_in,
                              void* d_out, int out_size, void* d_ws, size_t ws_size,
                              hipStream_t stream) {
    const float* pose3d    = (const float*)d_in[0];
    const float* bone_2d   = (const float*)d_in[1];
    const float* lift_dirs = (const float*)d_in[2];
    const float* R_drone   = (const float*)d_in[3];
    const float* C_drone   = (const float*)d_in[4];
    const float* bone_len  = (const float*)d_in[5];
    const float* R_cam     = (const float*)d_in[6];
    float* out = (float*)d_out;
    float* partials = (float*)d_ws;

    const int W = in_sizes[3] / 9;       // R_drone is (W,3,3)
    const int grid = (W + FR - 1) / FR;  // 2185 for W=131072

    pose_loss_kernel<<<grid, 256, 0, stream>>>(
        pose3d, bone_2d, lift_dirs, R_drone, C_drone, bone_len, R_cam, partials, W);
    final_reduce_kernel<<<1, 256, 0, stream>>>(partials, out, grid);
}

// Round 18
// 23.948 us; speedup vs baseline: 2.0915x; 1.1384x over previous
//
#include <hip/hip_runtime.h>

namespace {

typedef float f2 __attribute__((ext_vector_type(2)));

constexpr int FR = 64;    // frames per block

constexpr float F_F  = 512.0f;
constexpr float PX_F = 512.0f;
constexpr float PY_F = 288.0f;
constexpr float EPS_F = 1e-8f;

// weights folded with per-loss divisors
constexpr float WPROJ   = 0.25f / (2.0f * 21.0f);
constexpr float WLIFT   = 0.25f / (3.0f * 21.0f);
constexpr float WBONE   = 0.25f / 20.0f;
constexpr float WSMOOTH = 0.25f / (3.0f * 21.0f);

__device__ __forceinline__ double block_reduce(double val) {
    __shared__ double smem[16];
    const int lane = threadIdx.x & 63;
    const int wid  = threadIdx.x >> 6;
    #pragma unroll
    for (int off = 32; off > 0; off >>= 1)
        val += __shfl_down(val, off, 64);
    if (lane == 0) smem[wid] = val;
    __syncthreads();
    if (wid == 0) {
        const int nw = blockDim.x >> 6;
        val = (lane < nw) ? smem[lane] : 0.0;
        #pragma unroll
        for (int off = 32; off > 0; off >>= 1)
            val += __shfl_down(val, off, 64);
    }
    return val;
}

__global__ __launch_bounds__(256) void pose_loss_kernel(
    const float* __restrict__ pose3d,      // (W+1, 3, 21)
    const float* __restrict__ bone_2d,     // (W, 2, 21)
    const float* __restrict__ lift_dirs,   // (W, 3, 20)
    const float* __restrict__ R_drone,     // (W, 3, 3)
    const float* __restrict__ C_drone,     // (W, 3, 1)
    const float* __restrict__ bone_len,    // (20,)
    const float* __restrict__ R_cam,       // (3,3)
    float* __restrict__ partials,          // (gridDim.x,)
    int W)
{
    // pose 16.6 KB + M 3 KB -> ~19.7 KB -> 8 blocks/CU by LDS
    __shared__ alignas(16) float s_pose[(FR + 2) * 63 + 2];
    // permuted per-frame M row (stride 12):
    // [0..1]={M0,M3} [2..3]={M1,M4} [4..5]={M2,M5} [6..7]={MC0,MC1}
    // [8..11]={M6,M7,M8,MC2}
    __shared__ alignas(16) float s_M[FR * 12];

    const int tid = threadIdx.x;
    const int w0  = blockIdx.x * FR;
    const int nF  = min(FR, W - w0);
    const int nPoseF = min(FR + 2, W + 1 - w0);

    // ---------- stage pose (coalesced float4; base w0*63 is 16B-aligned) ----------
    {
        const float* src = pose3d + (size_t)w0 * 63;
        const int nfl = nPoseF * 63;
        const int n4 = nfl >> 2;
        const float4* s4 = (const float4*)src;
        float4* d4 = (float4*)s_pose;
        for (int i = tid; i < n4; i += 256) d4[i] = s4[i];
        for (int i = (n4 << 2) + tid; i < nfl; i += 256) s_pose[i] = src[i];
    }

    // ---------- per-frame M = R_cam @ Rd^T, MC = M @ C (threads 0..nF-1) ----------
    if (tid < nF) {
        const float* Rd = R_drone + (size_t)(w0 + tid) * 9;
        float rd[9];
        #pragma unroll
        for (int k = 0; k < 9; ++k) rd[k] = Rd[k];
        float rc[9];
        #pragma unroll
        for (int k = 0; k < 9; ++k) rc[k] = R_cam[k];   // uniform -> s_load
        float M[9];
        #pragma unroll
        for (int i = 0; i < 3; ++i)
            #pragma unroll
            for (int k = 0; k < 3; ++k)
                M[i * 3 + k] = rc[i * 3 + 0] * rd[k * 3 + 0]
                             + rc[i * 3 + 1] * rd[k * 3 + 1]
                             + rc[i * 3 + 2] * rd[k * 3 + 2];
        const float* Cp = C_drone + (size_t)(w0 + tid) * 3;
        const float C0 = Cp[0], C1 = Cp[1], C2 = Cp[2];
        float MC[3];
        #pragma unroll
        for (int i = 0; i < 3; ++i)
            MC[i] = M[i * 3 + 0] * C0 + M[i * 3 + 1] * C1 + M[i * 3 + 2] * C2;
        float* mb = s_M + tid * 12;
        mb[0] = M[0]; mb[1] = M[3]; mb[2]  = M[1]; mb[3]  = M[4];
        mb[4] = M[2]; mb[5] = M[5]; mb[6]  = MC[0]; mb[7] = MC[1];
        mb[8] = M[6]; mb[9] = M[7]; mb[10] = M[8]; mb[11] = MC[2];
    }
    __syncthreads();

    // 4 independent accumulators: break the serial FMA chain on `partial`
    float accP = 0.0f, accL = 0.0f, accB = 0.0f, accS = 0.0f;

    // fixed-j mapping: 252 active threads = 12 frame-groups x 21 joints
    if (tid < 252) {
        const int j = tid % 21;
        const int g = tid / 21;
        const bool hasBone = (j < 20);
        const float blj = hasBone ? bone_len[j] : 0.0f;

        // strength-reduced stream pointers (stepped by 12 frames/iter)
        const float* b2p = bone_2d   + (size_t)(w0 + g) * 42 + j;
        const float* lfp = lift_dirs + (size_t)(w0 + g) * 60 + j;

        for (int wl = g; wl < nF; wl += 12,
             b2p += 12 * 42, lfp += 12 * 60) {
            const int w = w0 + wl;
            const float* P0 = s_pose + wl * 63;
            const float* P1 = P0 + 63;
            const float* mb = s_M + wl * 12;

            const float x0 = P1[j], y0 = P1[21 + j], z0 = P1[42 + j];

            // ---- projection (pk math; fast rcp) ----
            {
                const f2 A = *(const f2*)(mb + 0);
                const f2 B = *(const f2*)(mb + 2);
                const f2 C = *(const f2*)(mb + 4);
                const f2 D = *(const f2*)(mb + 6);
                const float4 E = *(const float4*)(mb + 8);   // M6,M7,M8,MC2
                f2 c01 = A * x0 + B * y0 + C * z0 - D;
                const float c2 = E.x * x0 + E.y * y0 + E.z * z0 - E.w;
                const float invz = __builtin_amdgcn_rcpf(c2);
                f2 uv = c01 * (F_F * invz) + (f2){PX_F, PY_F};
                const f2 duv = uv - (f2){b2p[0], b2p[21]};
                accP += duv.x * duv.x + duv.y * duv.y;
            }

            if (hasBone) {
                // ---- lift (frame w+1 bone direction) ----
                const float ax = P1[j + 1]      - x0;
                const float ay = P1[21 + j + 1] - y0;
                const float az = P1[42 + j + 1] - z0;
                const float q  = ax * ax + ay * ay + az * az;
                const float inv = __builtin_amdgcn_rcpf(
                                      __builtin_amdgcn_sqrtf(q) + EPS_F);
                const float lx = lfp[0]  - ax * inv;
                const float ly = lfp[20] - ay * inv;
                const float lz = lfp[40] - az * inv;
                accL += lx * lx + ly * ly + lz * lz;

                // ---- bone (frame w) ----
                const float bx = P0[j + 1]      - P0[j];
                const float by = P0[21 + j + 1] - P0[21 + j];
                const float bz = P0[42 + j + 1] - P0[42 + j];
                const float e = blj - (bx * bx + by * by + bz * bz);
                accB += e * e;
                if (w == W - 1) {              // frame W == P1 here; |bone|^2 == q
                    const float e2 = blj - q;
                    accB += e2 * e2;
                }
            }

            // ---- smoothness (t = w) ----
            if (w < W - 1) {
                const float* P2 = P0 + 126;
                const float sx = P2[j]      - 2.0f * x0 + P0[j];
                const float sy = P2[21 + j] - 2.0f * y0 + P0[21 + j];
                const float sz = P2[42 + j] - 2.0f * z0 + P0[42 + j];
                accS += sx * sx + sy * sy + sz * sz;
            }
        }
    }

    const float partial = WPROJ * accP + WLIFT * accL + WBONE * accB + WSMOOTH * accS;
    const double bsum = block_reduce((double)partial);
    if (tid == 0) partials[blockIdx.x] = (float)bsum;
}

__global__ __launch_bounds__(256) void final_reduce_kernel(
    const float* __restrict__ partials, float* __restrict__ out, int n)
{
    double v = 0.0;
    const int n4 = n >> 2;
    const float4* p4 = (const float4*)partials;
    for (int i = threadIdx.x; i < n4; i += blockDim.x) {
        const float4 x = p4[i];
        v += (double)x.x + (double)x.y + (double)x.z + (double)x.w;
    }
    for (int i = (n4 << 2) + threadIdx.x; i < n; i += blockDim.x)
        v += (double)partials[i];
    v = block_reduce(v);
    if (threadIdx.x == 0) out[0] = (float)v;
}

}  // namespace

extern "C" void kernel_launch(void* const* d_in, const int* in_sizes, int n_in,
                              void* d_out, int out_size, void* d_ws, size_t ws_size,
                              hipStream_t stream) {
    const float* pose3d    = (const float*)d_in[0];
    const float* bone_2d   = (const float*)d_in[1];
    const float* lift_dirs = (const float*)d_in[2];
    const float* R_drone   = (const float*)d_in[3];
    const float* C_drone   = (const float*)d_in[4];
    const float* bone_len  = (const float*)d_in[5];
    const float* R_cam     = (const float*)d_in[6];
    float* out = (float*)d_out;
    float* partials = (float*)d_ws;

    const int W = in_sizes[3] / 9;       // R_drone is (W,3,3)
    const int grid = (W + FR - 1) / FR;  // 2048 for W=131072

    pose_loss_kernel<<<grid, 256, 0, stream>>>(
        pose3d, bone_2d, lift_dirs, R_drone, C_drone, bone_len, R_cam, partials, W);
    final_reduce_kernel<<<1, 256, 0, stream>>>(partials, out, grid);
}